// Round 1
// baseline (400.372 us; speedup 1.0000x reference)
//
#include <hip/hip_runtime.h>
#include <math.h>

// Problem constants: B=16, K=4, T=64, N=128, F=16, H=32, NH=8, GH=32
// Sequences: 12288 = 2048 anchor + 2048 pos + 8192 neg. Graphs: 96 = 16+16+64.

__device__ __forceinline__ float fast_rcp(float x) { return __builtin_amdgcn_rcpf(x); }
__device__ __forceinline__ float sigm(float x)     { return fast_rcp(1.f + __expf(-x)); }
__device__ __forceinline__ float tanh_fast(float x){ return fmaf(2.f, fast_rcp(1.f + __expf(-2.f * x)), -1.f); }

#define REP32(M) M(0)M(1)M(2)M(3)M(4)M(5)M(6)M(7)M(8)M(9)M(10)M(11)M(12)M(13)M(14)M(15) \
                 M(16)M(17)M(18)M(19)M(20)M(21)M(22)M(23)M(24)M(25)M(26)M(27)M(28)M(29)M(30)M(31)

// ---------------------------------------------------------------------------
// LSTM: 8 sequences/block, 32 lanes per sequence, lane j owns hidden unit j.
// Weights (192 f32/lane) in VGPRs; h broadcast via ds_swizzle (or-mask = k).
// ---------------------------------------------------------------------------
__global__ __launch_bounds__(256, 2) void lstm_kernel(
    const float* __restrict__ anchor, const float* __restrict__ pos,
    const float* __restrict__ neg, const float* __restrict__ Wih,
    const float* __restrict__ Whh, const float* __restrict__ bias,
    float* __restrict__ hn)
{
    __shared__ float xs[8][64][16];   // 32 KB
    const int tid = threadIdx.x;
    const int grp = tid >> 5;
    const int j   = tid & 31;
    const int seq0 = blockIdx.x * 8;

    // Stage x for the block's 8 sequences: x[t,f] = src[t*2048 + f]
    {
        const int t = tid >> 2, q = tid & 3;
        #pragma unroll
        for (int sl = 0; sl < 8; ++sl) {
            int s = seq0 + sl;
            const float* src;
            if (s < 2048)      { src = anchor + ((s >> 7) * 131072 + (s & 127) * 16); }
            else if (s < 4096) { int s2 = s - 2048; src = pos + ((s2 >> 7) * 131072 + (s2 & 127) * 16); }
            else               { int s2 = s - 4096; src = neg + ((s2 >> 7) * 131072 + (s2 & 127) * 16); }
            float4 v = *reinterpret_cast<const float4*>(src + t * 2048 + q * 4);
            *reinterpret_cast<float4*>(&xs[sl][t][q * 4]) = v;
        }
    }

    // Weights into registers (rows j, 32+j, 64+j, 96+j of Wih/Whh -> gates i,f,g,o)
    float WI[16], WF[16], WG[16], WO[16];
    float UI[32], UF[32], UG[32], UO[32];
    {
        const float4* wv = reinterpret_cast<const float4*>(Wih);
        #pragma unroll
        for (int q = 0; q < 4; ++q) {
            float4 v;
            v = wv[j * 4 + q];        WI[q*4+0]=v.x; WI[q*4+1]=v.y; WI[q*4+2]=v.z; WI[q*4+3]=v.w;
            v = wv[(32 + j) * 4 + q]; WF[q*4+0]=v.x; WF[q*4+1]=v.y; WF[q*4+2]=v.z; WF[q*4+3]=v.w;
            v = wv[(64 + j) * 4 + q]; WG[q*4+0]=v.x; WG[q*4+1]=v.y; WG[q*4+2]=v.z; WG[q*4+3]=v.w;
            v = wv[(96 + j) * 4 + q]; WO[q*4+0]=v.x; WO[q*4+1]=v.y; WO[q*4+2]=v.z; WO[q*4+3]=v.w;
        }
        const float4* uv = reinterpret_cast<const float4*>(Whh);
        #pragma unroll
        for (int q = 0; q < 8; ++q) {
            float4 v;
            v = uv[j * 8 + q];        UI[q*4+0]=v.x; UI[q*4+1]=v.y; UI[q*4+2]=v.z; UI[q*4+3]=v.w;
            v = uv[(32 + j) * 8 + q]; UF[q*4+0]=v.x; UF[q*4+1]=v.y; UF[q*4+2]=v.z; UF[q*4+3]=v.w;
            v = uv[(64 + j) * 8 + q]; UG[q*4+0]=v.x; UG[q*4+1]=v.y; UG[q*4+2]=v.z; UG[q*4+3]=v.w;
            v = uv[(96 + j) * 8 + q]; UO[q*4+0]=v.x; UO[q*4+1]=v.y; UO[q*4+2]=v.z; UO[q*4+3]=v.w;
        }
    }
    const float bI = bias[j], bF = bias[32 + j], bG = bias[64 + j], bO = bias[96 + j];
    __syncthreads();

    float h = 0.f, c = 0.f;
    for (int t = 0; t < 64; ++t) {
        float zi = bI, zf = bF, zg = bG, zo = bO;
        const float* xp = &xs[grp][t][0];
        #pragma unroll
        for (int k0 = 0; k0 < 16; k0 += 4) {
            const float4 xq = *reinterpret_cast<const float4*>(xp + k0);
            zi = fmaf(WI[k0+0], xq.x, zi); zf = fmaf(WF[k0+0], xq.x, zf);
            zg = fmaf(WG[k0+0], xq.x, zg); zo = fmaf(WO[k0+0], xq.x, zo);
            zi = fmaf(WI[k0+1], xq.y, zi); zf = fmaf(WF[k0+1], xq.y, zf);
            zg = fmaf(WG[k0+1], xq.y, zg); zo = fmaf(WO[k0+1], xq.y, zo);
            zi = fmaf(WI[k0+2], xq.z, zi); zf = fmaf(WF[k0+2], xq.z, zf);
            zg = fmaf(WG[k0+2], xq.z, zg); zo = fmaf(WO[k0+2], xq.z, zo);
            zi = fmaf(WI[k0+3], xq.w, zi); zf = fmaf(WF[k0+3], xq.w, zf);
            zg = fmaf(WG[k0+3], xq.w, zg); zo = fmaf(WO[k0+3], xq.w, zo);
        }
        // recurrent part: broadcast h[k] from lane k of this 32-lane group
        #define RSTEP(K) { float hk = __int_as_float(__builtin_amdgcn_ds_swizzle(__float_as_int(h), ((K) << 5))); \
            zi = fmaf(UI[K], hk, zi); zf = fmaf(UF[K], hk, zf); \
            zg = fmaf(UG[K], hk, zg); zo = fmaf(UO[K], hk, zo); }
        REP32(RSTEP)
        #undef RSTEP
        const float ig = sigm(zi), fg = sigm(zf), gg = tanh_fast(zg), og = sigm(zo);
        c = fmaf(fg, c, ig * gg);
        h = og * tanh_fast(c);
    }
    hn[(seq0 + grp) * 32 + j] = h;
}

// ---------------------------------------------------------------------------
// GATv2 layer 1: one block per (graph, head). Writes per-head outputs.
// ---------------------------------------------------------------------------
__global__ __launch_bounds__(256) void gat1_kernel(
    const float* __restrict__ hn, const float* __restrict__ W1s,
    const float* __restrict__ W1d, const float* __restrict__ a1,
    const float* __restrict__ b1, float* __restrict__ h1heads)
{
    const int g = blockIdx.x >> 3, hd = blockIdx.x & 7;
    __shared__ float P[128][129];    // logits -> probs (pad 129: row scans conflict-free)
    __shared__ float FS[128][32];
    __shared__ float FD[128][32];
    __shared__ float HS[128][32];
    __shared__ float WS[32][32];
    __shared__ float WD[32][32];
    __shared__ float AV[32];
    __shared__ float RN[128];
    const int tid = threadIdx.x;

    // stage h tile + weights
    {
        const float4* src = reinterpret_cast<const float4*>(hn + g * 4096);
        #pragma unroll
        for (int i = 0; i < 4; ++i) {
            int idx4 = i * 256 + tid;
            float4 v = src[idx4];
            int n = idx4 >> 3, k0 = (idx4 & 7) * 4;
            *reinterpret_cast<float4*>(&HS[n][k0]) = v;
        }
        const float4* ws4 = reinterpret_cast<const float4*>(W1s + hd * 1024);
        const float4* wd4 = reinterpret_cast<const float4*>(W1d + hd * 1024);
        {
            float4 v = ws4[tid];
            int k = tid >> 3, o0 = (tid & 7) * 4;
            *reinterpret_cast<float4*>(&WS[k][o0]) = v;
            v = wd4[tid];
            *reinterpret_cast<float4*>(&WD[k][o0]) = v;
        }
        if (tid < 32) AV[tid] = a1[hd * 32 + tid];
    }
    __syncthreads();

    // fs = h@Ws, fd = h@Wd ; thread = (o, 16-row slab); W columns in registers
    {
        const int o = tid & 31, nb = tid >> 5;
        float wcs[32], wcd[32];
        #pragma unroll
        for (int k = 0; k < 32; ++k) { wcs[k] = WS[k][o]; wcd[k] = WD[k][o]; }
        #pragma unroll 1
        for (int n = nb * 16; n < nb * 16 + 16; ++n) {
            float a0 = 0.f, a1_ = 0.f, b0 = 0.f, b1_ = 0.f;
            #pragma unroll
            for (int k0 = 0; k0 < 32; k0 += 4) {
                const float4 hv = *reinterpret_cast<const float4*>(&HS[n][k0]);
                a0 = fmaf(hv.x, wcs[k0+0], a0); b0 = fmaf(hv.x, wcd[k0+0], b0);
                a1_ = fmaf(hv.y, wcs[k0+1], a1_); b1_ = fmaf(hv.y, wcd[k0+1], b1_);
                a0 = fmaf(hv.z, wcs[k0+2], a0); b0 = fmaf(hv.z, wcd[k0+2], b0);
                a1_ = fmaf(hv.w, wcs[k0+3], a1_); b1_ = fmaf(hv.w, wcd[k0+3], b1_);
            }
            FS[n][o] = a0 + a1_;
            FD[n][o] = b0 + b1_;
        }
    }
    __syncthreads();

    // logits: P[d][s] = sum_o a[o]*lrelu(fd[d][o]+fs[s][o]) ; 4-way ILP
    {
        const int d = tid >> 1, sbase = (tid & 1) * 64;
        float fdr[32], av[32];
        #pragma unroll
        for (int o = 0; o < 32; ++o) { fdr[o] = FD[d][o]; av[o] = AV[o]; }
        #pragma unroll 1
        for (int s = sbase; s < sbase + 64; ++s) {
            float c0 = 0.f, c1 = 0.f, c2 = 0.f, c3 = 0.f;
            #pragma unroll
            for (int o = 0; o < 32; o += 4) {
                const float4 fv = *reinterpret_cast<const float4*>(&FS[s][o]);
                float e;
                e = fdr[o+0] + fv.x; e = fmaxf(e, 0.2f * e); c0 = fmaf(av[o+0], e, c0);
                e = fdr[o+1] + fv.y; e = fmaxf(e, 0.2f * e); c1 = fmaf(av[o+1], e, c1);
                e = fdr[o+2] + fv.z; e = fmaxf(e, 0.2f * e); c2 = fmaf(av[o+2], e, c2);
                e = fdr[o+3] + fv.w; e = fmaxf(e, 0.2f * e); c3 = fmaf(av[o+3], e, c3);
            }
            P[d][s] = (c0 + c1) + (c2 + c3);
        }
    }
    __syncthreads();

    // row softmax over s != d (diagonal masked to 0 probability)
    if (tid < 128) {
        const int d = tid;
        float m = -1e30f;
        #pragma unroll 1
        for (int s = 0; s < 128; ++s) { float v = P[d][s]; m = (s == d) ? m : fmaxf(m, v); }
        float sum = 0.f;
        #pragma unroll 1
        for (int s = 0; s < 128; ++s) {
            float p = (s == d) ? 0.f : __expf(P[d][s] - m);
            P[d][s] = p; sum += p;
        }
        RN[d] = fast_rcp(sum);
    }
    __syncthreads();

    // out[d][o] = (sum_s p[d][s] * fs[s][o]) * rcpZ[d] + bias
    {
        const int d = tid >> 1, oh = (tid & 1) * 16;
        float acc[16];
        #pragma unroll
        for (int i = 0; i < 16; ++i) acc[i] = 0.f;
        #pragma unroll 1
        for (int s = 0; s < 128; ++s) {
            const float p = P[d][s];
            #pragma unroll
            for (int oo = 0; oo < 16; oo += 4) {
                const float4 fv = *reinterpret_cast<const float4*>(&FS[s][oh + oo]);
                acc[oo+0] = fmaf(p, fv.x, acc[oo+0]);
                acc[oo+1] = fmaf(p, fv.y, acc[oo+1]);
                acc[oo+2] = fmaf(p, fv.z, acc[oo+2]);
                acc[oo+3] = fmaf(p, fv.w, acc[oo+3]);
            }
        }
        const float rz = RN[d];
        float4* dst = reinterpret_cast<float4*>(h1heads + ((g * 8 + hd) * 128 + d) * 32 + oh);
        const float* bp = b1 + hd * 32 + oh;
        #pragma unroll
        for (int oo = 0; oo < 16; oo += 4) {
            float4 v;
            v.x = fmaf(acc[oo+0], rz, bp[oo+0]);
            v.y = fmaf(acc[oo+1], rz, bp[oo+1]);
            v.z = fmaf(acc[oo+2], rz, bp[oo+2]);
            v.w = fmaf(acc[oo+3], rz, bp[oo+3]);
            dst[oo >> 2] = v;
        }
    }
}

// ---------------------------------------------------------------------------
// GATv2 layer 2: one block per graph; fuses head-mean on load + node-mean pool.
// ---------------------------------------------------------------------------
__global__ __launch_bounds__(256) void gat2_kernel(
    const float* __restrict__ h1heads, const float* __restrict__ W2s,
    const float* __restrict__ W2d, const float* __restrict__ a2,
    const float* __restrict__ b2, float* __restrict__ pooled)
{
    const int g = blockIdx.x;
    __shared__ float P[128][129];
    __shared__ float FS[128][32];
    __shared__ float FD[128][32];
    __shared__ float HS[128][32];
    __shared__ float WS[32][32];
    __shared__ float WD[32][32];
    __shared__ float AV[32];
    __shared__ float RN[128];
    __shared__ float PART[8][33];
    const int tid = threadIdx.x;

    // stage: h1 = mean over 8 heads
    {
        #pragma unroll
        for (int i = 0; i < 4; ++i) {
            int idx4 = i * 256 + tid;
            float sx = 0.f, sy = 0.f, sz = 0.f, sw = 0.f;
            #pragma unroll
            for (int hd = 0; hd < 8; ++hd) {
                const float4* src = reinterpret_cast<const float4*>(h1heads + (g * 8 + hd) * 4096);
                float4 v = src[idx4];
                sx += v.x; sy += v.y; sz += v.z; sw += v.w;
            }
            int n = idx4 >> 3, k0 = (idx4 & 7) * 4;
            float4 r; r.x = sx * 0.125f; r.y = sy * 0.125f; r.z = sz * 0.125f; r.w = sw * 0.125f;
            *reinterpret_cast<float4*>(&HS[n][k0]) = r;
        }
        {
            const float4* ws4 = reinterpret_cast<const float4*>(W2s);
            const float4* wd4 = reinterpret_cast<const float4*>(W2d);
            float4 v = ws4[tid];
            int k = tid >> 3, o0 = (tid & 7) * 4;
            *reinterpret_cast<float4*>(&WS[k][o0]) = v;
            v = wd4[tid];
            *reinterpret_cast<float4*>(&WD[k][o0]) = v;
        }
        if (tid < 32) AV[tid] = a2[tid];
    }
    __syncthreads();

    {
        const int o = tid & 31, nb = tid >> 5;
        float wcs[32], wcd[32];
        #pragma unroll
        for (int k = 0; k < 32; ++k) { wcs[k] = WS[k][o]; wcd[k] = WD[k][o]; }
        #pragma unroll 1
        for (int n = nb * 16; n < nb * 16 + 16; ++n) {
            float a0 = 0.f, a1_ = 0.f, b0 = 0.f, b1_ = 0.f;
            #pragma unroll
            for (int k0 = 0; k0 < 32; k0 += 4) {
                const float4 hv = *reinterpret_cast<const float4*>(&HS[n][k0]);
                a0 = fmaf(hv.x, wcs[k0+0], a0); b0 = fmaf(hv.x, wcd[k0+0], b0);
                a1_ = fmaf(hv.y, wcs[k0+1], a1_); b1_ = fmaf(hv.y, wcd[k0+1], b1_);
                a0 = fmaf(hv.z, wcs[k0+2], a0); b0 = fmaf(hv.z, wcd[k0+2], b0);
                a1_ = fmaf(hv.w, wcs[k0+3], a1_); b1_ = fmaf(hv.w, wcd[k0+3], b1_);
            }
            FS[n][o] = a0 + a1_;
            FD[n][o] = b0 + b1_;
        }
    }
    __syncthreads();

    {
        const int d = tid >> 1, sbase = (tid & 1) * 64;
        float fdr[32], av[32];
        #pragma unroll
        for (int o = 0; o < 32; ++o) { fdr[o] = FD[d][o]; av[o] = AV[o]; }
        #pragma unroll 1
        for (int s = sbase; s < sbase + 64; ++s) {
            float c0 = 0.f, c1 = 0.f, c2 = 0.f, c3 = 0.f;
            #pragma unroll
            for (int o = 0; o < 32; o += 4) {
                const float4 fv = *reinterpret_cast<const float4*>(&FS[s][o]);
                float e;
                e = fdr[o+0] + fv.x; e = fmaxf(e, 0.2f * e); c0 = fmaf(av[o+0], e, c0);
                e = fdr[o+1] + fv.y; e = fmaxf(e, 0.2f * e); c1 = fmaf(av[o+1], e, c1);
                e = fdr[o+2] + fv.z; e = fmaxf(e, 0.2f * e); c2 = fmaf(av[o+2], e, c2);
                e = fdr[o+3] + fv.w; e = fmaxf(e, 0.2f * e); c3 = fmaf(av[o+3], e, c3);
            }
            P[d][s] = (c0 + c1) + (c2 + c3);
        }
    }
    __syncthreads();

    if (tid < 128) {
        const int d = tid;
        float m = -1e30f;
        #pragma unroll 1
        for (int s = 0; s < 128; ++s) { float v = P[d][s]; m = (s == d) ? m : fmaxf(m, v); }
        float sum = 0.f;
        #pragma unroll 1
        for (int s = 0; s < 128; ++s) {
            float p = (s == d) ? 0.f : __expf(P[d][s] - m);
            P[d][s] = p; sum += p;
        }
        RN[d] = fast_rcp(sum);
    }
    __syncthreads();

    // PV -> FD (reused as output tile)
    {
        const int d = tid >> 1, oh = (tid & 1) * 16;
        float acc[16];
        #pragma unroll
        for (int i = 0; i < 16; ++i) acc[i] = 0.f;
        #pragma unroll 1
        for (int s = 0; s < 128; ++s) {
            const float p = P[d][s];
            #pragma unroll
            for (int oo = 0; oo < 16; oo += 4) {
                const float4 fv = *reinterpret_cast<const float4*>(&FS[s][oh + oo]);
                acc[oo+0] = fmaf(p, fv.x, acc[oo+0]);
                acc[oo+1] = fmaf(p, fv.y, acc[oo+1]);
                acc[oo+2] = fmaf(p, fv.z, acc[oo+2]);
                acc[oo+3] = fmaf(p, fv.w, acc[oo+3]);
            }
        }
        const float rz = RN[d];
        const float* bp = b2 + oh;
        #pragma unroll
        for (int oo = 0; oo < 16; ++oo) FD[d][oh + oo] = fmaf(acc[oo], rz, bp[oo]);
    }
    __syncthreads();

    // pooled[g][o] = mean over n
    {
        const int o = tid & 31, nb = tid >> 5;
        float sp = 0.f;
        #pragma unroll 1
        for (int n = nb * 16; n < nb * 16 + 16; ++n) sp += FD[n][o];
        PART[nb][o] = sp;
    }
    __syncthreads();
    if (tid < 32) {
        float s = 0.f;
        #pragma unroll
        for (int q = 0; q < 8; ++q) s += PART[q][tid];
        pooled[g * 32 + tid] = s * (1.f / 128.f);
    }
}

// ---------------------------------------------------------------------------
// Final: cosine sims, contrastive loss, output assembly.
// ---------------------------------------------------------------------------
__global__ void final_kernel(const float* __restrict__ pooled,
                             const float* __restrict__ hideout,
                             const float* __restrict__ timestep,
                             float* __restrict__ out)
{
    const int b = threadIdx.x;
    __shared__ float lossArr[16];
    if (b < 16) {
        const float* A  = pooled + b * 32;
        const float* Pv = pooled + (16 + b) * 32;
        float av[32];
        float na = 0.f;
        #pragma unroll
        for (int i = 0; i < 32; ++i) { av[i] = A[i]; na += av[i] * av[i]; }
        float npv = 0.f, dp = 0.f;
        #pragma unroll
        for (int i = 0; i < 32; ++i) { float p = Pv[i]; npv += p * p; dp += av[i] * p; }
        const float eps = 1e-6f;
        const float ia = 1.f / fmaxf(sqrtf(na), eps);
        const float sp = dp * ia / fmaxf(sqrtf(npv), eps);
        float sn[4];
        #pragma unroll
        for (int k = 0; k < 4; ++k) {
            const float* Nv = pooled + (32 + b * 4 + k) * 32;
            float nn = 0.f, dn = 0.f;
            #pragma unroll
            for (int i = 0; i < 32; ++i) { float q = Nv[i]; nn += q * q; dn += av[i] * q; }
            sn[k] = dn * ia / fmaxf(sqrtf(nn), eps);
        }
        float m = sp;
        #pragma unroll
        for (int k = 0; k < 4; ++k) m = fmaxf(m, sn[k]);
        float Z = expf(sp - m);
        #pragma unroll
        for (int k = 0; k < 4; ++k) Z += expf(sn[k] - m);
        lossArr[b] = logf(Z) + m - sp;   // lse - sim_pos
        float* r = out + b * 35;
        #pragma unroll
        for (int i = 0; i < 32; ++i) r[i] = av[i];
        r[32] = hideout[b * 2];
        r[33] = hideout[b * 2 + 1];
        r[34] = timestep[b];
    }
    __syncthreads();
    if (b == 0) {
        float s = 0.f;
        #pragma unroll
        for (int i = 0; i < 16; ++i) s += lossArr[i];
        out[560] = s * (1.f / 16.f);
    }
}

extern "C" void kernel_launch(void* const* d_in, const int* in_sizes, int n_in,
                              void* d_out, int out_size, void* d_ws, size_t ws_size,
                              hipStream_t stream) {
    const float* anchor   = (const float*)d_in[0];
    const float* pos      = (const float*)d_in[1];
    const float* neg      = (const float*)d_in[2];
    const float* hideout  = (const float*)d_in[3];
    const float* timestep = (const float*)d_in[4];
    const float* Wih      = (const float*)d_in[5];
    const float* Whh      = (const float*)d_in[6];
    const float* b_lstm   = (const float*)d_in[7];
    const float* W1s      = (const float*)d_in[8];
    const float* W1d      = (const float*)d_in[9];
    const float* a1       = (const float*)d_in[10];
    const float* b1       = (const float*)d_in[11];
    const float* W2s      = (const float*)d_in[12];
    const float* W2d      = (const float*)d_in[13];
    const float* a2       = (const float*)d_in[14];
    const float* b2       = (const float*)d_in[15];
    float* out = (float*)d_out;

    char* ws = (char*)d_ws;
    float* hn      = (float*)(ws);                       // 12288*32*4   = 1,572,864 B
    float* h1heads = (float*)(ws + 1605632);             // 96*8*128*32*4 = 12,582,912 B
    float* pooled  = (float*)(ws + 14188544);            // 96*32*4      = 12,288 B

    hipLaunchKernelGGL(lstm_kernel,  dim3(1536), dim3(256), 0, stream,
                       anchor, pos, neg, Wih, Whh, b_lstm, hn);
    hipLaunchKernelGGL(gat1_kernel,  dim3(768),  dim3(256), 0, stream,
                       hn, W1s, W1d, a1, b1, h1heads);
    hipLaunchKernelGGL(gat2_kernel,  dim3(96),   dim3(256), 0, stream,
                       h1heads, W2s, W2d, a2, b2, pooled);
    hipLaunchKernelGGL(final_kernel, dim3(1),    dim3(64),  0, stream,
                       pooled, hideout, timestep, out);
}

// Round 2
// 324.179 us; speedup vs baseline: 1.2350x; 1.2350x over previous
//
#include <hip/hip_runtime.h>
#include <math.h>

// Problem constants: B=16, K=4, T=64, N=128, F=16, H=32, NH=8, GH=32
// Sequences: 12288 = 2048 anchor + 2048 pos + 8192 neg. Graphs: 96 = 16+16+64.

typedef __bf16 bf16x8 __attribute__((ext_vector_type(8)));
typedef float  f32x4  __attribute__((ext_vector_type(4)));

__device__ __forceinline__ float fast_rcp(float x) { return __builtin_amdgcn_rcpf(x); }
__device__ __forceinline__ float sigm(float x)     { return fast_rcp(1.f + __expf(-x)); }
__device__ __forceinline__ float tanh_fast(float x){ return fmaf(2.f, fast_rcp(1.f + __expf(-2.f * x)), -1.f); }

// ---------------------------------------------------------------------------
// LSTM via MFMA: 768 blocks x 128 threads (2 waves). Block owns 16 sequences.
// Per step: Z[16 seqs][128 gates] = bias + x@Wih^T (bf16, W split hi/lo)
//                                        + h@Whh^T (full 3-term split-bf16).
// Wave wid owns gate-tiles {2q+wid}: cols q*32 + wid*16 + (lane&15), q=0..3,
// so each lane holds all 4 gates for (4 seqs x 1 hidden unit) in C/D layout
// (col=lane&15, row=(lane>>4)*4+reg  [HW-verified]). c-state lives in VGPRs.
// h is exchanged through a 4KB XOR-swizzled LDS buffer (hi|lo packed u32).
// k-slot convention (k = 8*(lane>>4)+i) is used identically for A and B
// fragments -> result is invariant to the HW's true k permutation.
// ---------------------------------------------------------------------------
__global__ __launch_bounds__(128) void lstm_mfma_kernel(
    const float* __restrict__ anchor, const float* __restrict__ pos,
    const float* __restrict__ neg, const float* __restrict__ Wih,
    const float* __restrict__ Whh, const float* __restrict__ bias,
    float* __restrict__ hn)
{
    __shared__ unsigned int Hbuf[2][16 * 32];   // [dbuf][m][j] packed bf16 hi|lo
    const int tid  = threadIdx.x;
    const int lane = tid & 63;
    const int wid  = tid >> 6;         // 0/1: which j-half this wave owns
    const int l15  = lane & 15;
    const int g4   = lane >> 4;

    // zero both h buffers (h0 = 0)
    for (int i = tid; i < 2 * 16 * 32; i += 128) ((unsigned int*)Hbuf)[i] = 0u;

    // ---- B-fragments: Whh (hi+lo) and Wih (hi+lo), plus bias ----
    bf16x8 whh_hi[4], whh_lo[4], wih_hi[4], wih_lo[4];
    f32x4 bvec[4];
    #pragma unroll
    for (int q = 0; q < 4; ++q) {
        const int c = q * 32 + wid * 16 + l15;   // output col = gate q, unit j
        const float bq = bias[c];
        bvec[q][0] = bq; bvec[q][1] = bq; bvec[q][2] = bq; bvec[q][3] = bq;
        const float* wr = Whh + c * 32 + g4 * 8; // B[k][c] = Whh[c][k], k=8*g4+i
        #pragma unroll
        for (int i = 0; i < 8; ++i) {
            float w = wr[i];
            __bf16 hi = (__bf16)w;
            whh_hi[q][i] = hi;
            whh_lo[q][i] = (__bf16)(w - (float)hi);
        }
        if (g4 < 2) {                            // k<16 slots carry Wih
            const float* wr2 = Wih + c * 16 + g4 * 8;
            #pragma unroll
            for (int i = 0; i < 8; ++i) {
                float w = wr2[i];
                __bf16 hi = (__bf16)w;
                wih_hi[q][i] = hi;
                wih_lo[q][i] = (__bf16)(w - (float)hi);
            }
        } else {                                 // zero-pad k>=16
            #pragma unroll
            for (int i = 0; i < 8; ++i) {
                wih_hi[q][i] = (__bf16)0.f; wih_lo[q][i] = (__bf16)0.f;
            }
        }
    }

    // ---- x source pointer: seq s = blk*16 + (lane&15), feature f = 8*g4+i ----
    const int s = blockIdx.x * 16 + l15;
    const float* xbase; int sl;
    if (s < 2048)      { xbase = anchor; sl = s; }
    else if (s < 4096) { xbase = pos;    sl = s - 2048; }
    else               { xbase = neg;    sl = s - 4096; }
    const bool xact = (g4 < 2);
    const float* xp = xbase + (sl >> 7) * 131072 + (sl & 127) * 16 + (xact ? g4 * 8 : 0);

    float4 xa, xb, xa_n, xb_n;
    xa_n = make_float4(0.f, 0.f, 0.f, 0.f); xb_n = xa_n;
    if (xact) { xa = *(const float4*)(xp); xb = *(const float4*)(xp + 4); }
    else      { xa = xa_n; xb = xb_n; }

    float cst[4] = {0.f, 0.f, 0.f, 0.f};
    float hv[4]  = {0.f, 0.f, 0.f, 0.f};
    const int jw = wid * 16 + l15;        // absolute hidden-unit index this lane owns
    int cur = 0;
    __syncthreads();                      // Hbuf zeros visible

    for (int t = 0; t < 64; ++t) {
        // prefetch next step's x
        if (xact && t < 63) {
            const float* p = xp + (t + 1) * 2048;
            xa_n = *(const float4*)(p); xb_n = *(const float4*)(p + 4);
        }
        // x A-fragment (rows m=l15, k-slots 8*g4+i; zeros for k>=16)
        bf16x8 ax;
        if (xact) {
            ax[0]=(__bf16)xa.x; ax[1]=(__bf16)xa.y; ax[2]=(__bf16)xa.z; ax[3]=(__bf16)xa.w;
            ax[4]=(__bf16)xb.x; ax[5]=(__bf16)xb.y; ax[6]=(__bf16)xb.z; ax[7]=(__bf16)xb.w;
        } else {
            #pragma unroll
            for (int i = 0; i < 8; ++i) ax[i] = (__bf16)0.f;
        }

        // h A-fragments: rows m=l15, k=j=8*g4+i; XOR-swizzled chunks
        {
            const int m = l15;
            const int c0 = g4 * 2;
            const int swz = (m & 3) << 1;
            const unsigned int* hb = Hbuf[cur];
            uint4 v0 = *(const uint4*)(hb + m * 32 + ((c0 ^ swz) << 2));
            uint4 v1 = *(const uint4*)(hb + m * 32 + (((c0 + 1) ^ swz) << 2));
            union { unsigned int w[4]; bf16x8 v; } ahi, alo;
            ahi.w[0] = __builtin_amdgcn_perm(v0.y, v0.x, 0x05040100u);
            ahi.w[1] = __builtin_amdgcn_perm(v0.w, v0.z, 0x05040100u);
            ahi.w[2] = __builtin_amdgcn_perm(v1.y, v1.x, 0x05040100u);
            ahi.w[3] = __builtin_amdgcn_perm(v1.w, v1.z, 0x05040100u);
            alo.w[0] = __builtin_amdgcn_perm(v0.y, v0.x, 0x07060302u);
            alo.w[1] = __builtin_amdgcn_perm(v0.w, v0.z, 0x07060302u);
            alo.w[2] = __builtin_amdgcn_perm(v1.y, v1.x, 0x07060302u);
            alo.w[3] = __builtin_amdgcn_perm(v1.w, v1.z, 0x07060302u);

            f32x4 acc[4];
            #pragma unroll
            for (int q = 0; q < 4; ++q) {
                f32x4 a = __builtin_amdgcn_mfma_f32_16x16x32_bf16(ax,    wih_hi[q], bvec[q], 0, 0, 0);
                a = __builtin_amdgcn_mfma_f32_16x16x32_bf16(ax,    wih_lo[q], a, 0, 0, 0);
                a = __builtin_amdgcn_mfma_f32_16x16x32_bf16(ahi.v, whh_hi[q], a, 0, 0, 0);
                a = __builtin_amdgcn_mfma_f32_16x16x32_bf16(ahi.v, whh_lo[q], a, 0, 0, 0);
                a = __builtin_amdgcn_mfma_f32_16x16x32_bf16(alo.v, whh_hi[q], a, 0, 0, 0);
                acc[q] = a;
            }

            // activations + h pack/write (rows m = g4*4+r, unit jw)
            unsigned int* wb = Hbuf[cur ^ 1];
            #pragma unroll
            for (int r = 0; r < 4; ++r) {
                float zi = acc[0][r], zf = acc[1][r], zg = acc[2][r], zo = acc[3][r];
                float cn = fmaf(sigm(zf), cst[r], sigm(zi) * tanh_fast(zg));
                cst[r] = cn;
                float h = sigm(zo) * tanh_fast(cn);
                hv[r] = h;
                __bf16 hh = (__bf16)h;
                __bf16 hl = (__bf16)(h - (float)hh);
                unsigned int pk = (unsigned int)__builtin_bit_cast(unsigned short, hh)
                                | ((unsigned int)__builtin_bit_cast(unsigned short, hl) << 16);
                const int mm = g4 * 4 + r;
                const int sw = (mm & 3) << 1;
                wb[mm * 32 + (((jw >> 2) ^ sw) << 2) + (jw & 3)] = pk;
            }
        }
        __syncthreads();
        cur ^= 1;
        xa = xa_n; xb = xb_n;
    }

    // epilogue: hn[s][j]
    #pragma unroll
    for (int r = 0; r < 4; ++r) {
        const int mm = g4 * 4 + r;
        hn[(blockIdx.x * 16 + mm) * 32 + jw] = hv[r];
    }
}

// ---------------------------------------------------------------------------
// GATv2 layer 1: one block per (graph, head). Writes per-head outputs.
// ---------------------------------------------------------------------------
__global__ __launch_bounds__(256) void gat1_kernel(
    const float* __restrict__ hn, const float* __restrict__ W1s,
    const float* __restrict__ W1d, const float* __restrict__ a1,
    const float* __restrict__ b1, float* __restrict__ h1heads)
{
    const int g = blockIdx.x >> 3, hd = blockIdx.x & 7;
    __shared__ float P[128][129];    // logits -> probs (pad 129: row scans conflict-free)
    __shared__ float FS[128][32];
    __shared__ float FD[128][32];
    __shared__ float HS[128][32];
    __shared__ float WS[32][32];
    __shared__ float WD[32][32];
    __shared__ float AV[32];
    __shared__ float RN[128];
    const int tid = threadIdx.x;

    // stage h tile + weights
    {
        const float4* src = reinterpret_cast<const float4*>(hn + g * 4096);
        #pragma unroll
        for (int i = 0; i < 4; ++i) {
            int idx4 = i * 256 + tid;
            float4 v = src[idx4];
            int n = idx4 >> 3, k0 = (idx4 & 7) * 4;
            *reinterpret_cast<float4*>(&HS[n][k0]) = v;
        }
        const float4* ws4 = reinterpret_cast<const float4*>(W1s + hd * 1024);
        const float4* wd4 = reinterpret_cast<const float4*>(W1d + hd * 1024);
        {
            float4 v = ws4[tid];
            int k = tid >> 3, o0 = (tid & 7) * 4;
            *reinterpret_cast<float4*>(&WS[k][o0]) = v;
            v = wd4[tid];
            *reinterpret_cast<float4*>(&WD[k][o0]) = v;
        }
        if (tid < 32) AV[tid] = a1[hd * 32 + tid];
    }
    __syncthreads();

    // fs = h@Ws, fd = h@Wd ; thread = (o, 16-row slab); W columns in registers
    {
        const int o = tid & 31, nb = tid >> 5;
        float wcs[32], wcd[32];
        #pragma unroll
        for (int k = 0; k < 32; ++k) { wcs[k] = WS[k][o]; wcd[k] = WD[k][o]; }
        #pragma unroll 1
        for (int n = nb * 16; n < nb * 16 + 16; ++n) {
            float a0 = 0.f, a1_ = 0.f, b0 = 0.f, b1_ = 0.f;
            #pragma unroll
            for (int k0 = 0; k0 < 32; k0 += 4) {
                const float4 hv = *reinterpret_cast<const float4*>(&HS[n][k0]);
                a0 = fmaf(hv.x, wcs[k0+0], a0); b0 = fmaf(hv.x, wcd[k0+0], b0);
                a1_ = fmaf(hv.y, wcs[k0+1], a1_); b1_ = fmaf(hv.y, wcd[k0+1], b1_);
                a0 = fmaf(hv.z, wcs[k0+2], a0); b0 = fmaf(hv.z, wcd[k0+2], b0);
                a1_ = fmaf(hv.w, wcs[k0+3], a1_); b1_ = fmaf(hv.w, wcd[k0+3], b1_);
            }
            FS[n][o] = a0 + a1_;
            FD[n][o] = b0 + b1_;
        }
    }
    __syncthreads();

    // logits: P[d][s] = sum_o a[o]*lrelu(fd[d][o]+fs[s][o]) ; 4-way ILP
    {
        const int d = tid >> 1, sbase = (tid & 1) * 64;
        float fdr[32], av[32];
        #pragma unroll
        for (int o = 0; o < 32; ++o) { fdr[o] = FD[d][o]; av[o] = AV[o]; }
        #pragma unroll 1
        for (int s = sbase; s < sbase + 64; ++s) {
            float c0 = 0.f, c1 = 0.f, c2 = 0.f, c3 = 0.f;
            #pragma unroll
            for (int o = 0; o < 32; o += 4) {
                const float4 fv = *reinterpret_cast<const float4*>(&FS[s][o]);
                float e;
                e = fdr[o+0] + fv.x; e = fmaxf(e, 0.2f * e); c0 = fmaf(av[o+0], e, c0);
                e = fdr[o+1] + fv.y; e = fmaxf(e, 0.2f * e); c1 = fmaf(av[o+1], e, c1);
                e = fdr[o+2] + fv.z; e = fmaxf(e, 0.2f * e); c2 = fmaf(av[o+2], e, c2);
                e = fdr[o+3] + fv.w; e = fmaxf(e, 0.2f * e); c3 = fmaf(av[o+3], e, c3);
            }
            P[d][s] = (c0 + c1) + (c2 + c3);
        }
    }
    __syncthreads();

    // row softmax over s != d (diagonal masked to 0 probability)
    if (tid < 128) {
        const int d = tid;
        float m = -1e30f;
        #pragma unroll 1
        for (int s = 0; s < 128; ++s) { float v = P[d][s]; m = (s == d) ? m : fmaxf(m, v); }
        float sum = 0.f;
        #pragma unroll 1
        for (int s = 0; s < 128; ++s) {
            float p = (s == d) ? 0.f : __expf(P[d][s] - m);
            P[d][s] = p; sum += p;
        }
        RN[d] = fast_rcp(sum);
    }
    __syncthreads();

    // out[d][o] = (sum_s p[d][s] * fs[s][o]) * rcpZ[d] + bias
    {
        const int d = tid >> 1, oh = (tid & 1) * 16;
        float acc[16];
        #pragma unroll
        for (int i = 0; i < 16; ++i) acc[i] = 0.f;
        #pragma unroll 1
        for (int s = 0; s < 128; ++s) {
            const float p = P[d][s];
            #pragma unroll
            for (int oo = 0; oo < 16; oo += 4) {
                const float4 fv = *reinterpret_cast<const float4*>(&FS[s][oh + oo]);
                acc[oo+0] = fmaf(p, fv.x, acc[oo+0]);
                acc[oo+1] = fmaf(p, fv.y, acc[oo+1]);
                acc[oo+2] = fmaf(p, fv.z, acc[oo+2]);
                acc[oo+3] = fmaf(p, fv.w, acc[oo+3]);
            }
        }
        const float rz = RN[d];
        float4* dst = reinterpret_cast<float4*>(h1heads + ((g * 8 + hd) * 128 + d) * 32 + oh);
        const float* bp = b1 + hd * 32 + oh;
        #pragma unroll
        for (int oo = 0; oo < 16; oo += 4) {
            float4 v;
            v.x = fmaf(acc[oo+0], rz, bp[oo+0]);
            v.y = fmaf(acc[oo+1], rz, bp[oo+1]);
            v.z = fmaf(acc[oo+2], rz, bp[oo+2]);
            v.w = fmaf(acc[oo+3], rz, bp[oo+3]);
            dst[oo >> 2] = v;
        }
    }
}

// ---------------------------------------------------------------------------
// GATv2 layer 2: one block per graph; fuses head-mean on load + node-mean pool.
// ---------------------------------------------------------------------------
__global__ __launch_bounds__(256) void gat2_kernel(
    const float* __restrict__ h1heads, const float* __restrict__ W2s,
    const float* __restrict__ W2d, const float* __restrict__ a2,
    const float* __restrict__ b2, float* __restrict__ pooled)
{
    const int g = blockIdx.x;
    __shared__ float P[128][129];
    __shared__ float FS[128][32];
    __shared__ float FD[128][32];
    __shared__ float HS[128][32];
    __shared__ float WS[32][32];
    __shared__ float WD[32][32];
    __shared__ float AV[32];
    __shared__ float RN[128];
    __shared__ float PART[8][33];
    const int tid = threadIdx.x;

    // stage: h1 = mean over 8 heads
    {
        #pragma unroll
        for (int i = 0; i < 4; ++i) {
            int idx4 = i * 256 + tid;
            float sx = 0.f, sy = 0.f, sz = 0.f, sw = 0.f;
            #pragma unroll
            for (int hd = 0; hd < 8; ++hd) {
                const float4* src = reinterpret_cast<const float4*>(h1heads + (g * 8 + hd) * 4096);
                float4 v = src[idx4];
                sx += v.x; sy += v.y; sz += v.z; sw += v.w;
            }
            int n = idx4 >> 3, k0 = (idx4 & 7) * 4;
            float4 r; r.x = sx * 0.125f; r.y = sy * 0.125f; r.z = sz * 0.125f; r.w = sw * 0.125f;
            *reinterpret_cast<float4*>(&HS[n][k0]) = r;
        }
        {
            const float4* ws4 = reinterpret_cast<const float4*>(W2s);
            const float4* wd4 = reinterpret_cast<const float4*>(W2d);
            float4 v = ws4[tid];
            int k = tid >> 3, o0 = (tid & 7) * 4;
            *reinterpret_cast<float4*>(&WS[k][o0]) = v;
            v = wd4[tid];
            *reinterpret_cast<float4*>(&WD[k][o0]) = v;
        }
        if (tid < 32) AV[tid] = a2[tid];
    }
    __syncthreads();

    {
        const int o = tid & 31, nb = tid >> 5;
        float wcs[32], wcd[32];
        #pragma unroll
        for (int k = 0; k < 32; ++k) { wcs[k] = WS[k][o]; wcd[k] = WD[k][o]; }
        #pragma unroll 1
        for (int n = nb * 16; n < nb * 16 + 16; ++n) {
            float a0 = 0.f, a1_ = 0.f, b0 = 0.f, b1_ = 0.f;
            #pragma unroll
            for (int k0 = 0; k0 < 32; k0 += 4) {
                const float4 hv = *reinterpret_cast<const float4*>(&HS[n][k0]);
                a0 = fmaf(hv.x, wcs[k0+0], a0); b0 = fmaf(hv.x, wcd[k0+0], b0);
                a1_ = fmaf(hv.y, wcs[k0+1], a1_); b1_ = fmaf(hv.y, wcd[k0+1], b1_);
                a0 = fmaf(hv.z, wcs[k0+2], a0); b0 = fmaf(hv.z, wcd[k0+2], b0);
                a1_ = fmaf(hv.w, wcs[k0+3], a1_); b1_ = fmaf(hv.w, wcd[k0+3], b1_);
            }
            FS[n][o] = a0 + a1_;
            FD[n][o] = b0 + b1_;
        }
    }
    __syncthreads();

    {
        const int d = tid >> 1, sbase = (tid & 1) * 64;
        float fdr[32], av[32];
        #pragma unroll
        for (int o = 0; o < 32; ++o) { fdr[o] = FD[d][o]; av[o] = AV[o]; }
        #pragma unroll 1
        for (int s = sbase; s < sbase + 64; ++s) {
            float c0 = 0.f, c1 = 0.f, c2 = 0.f, c3 = 0.f;
            #pragma unroll
            for (int o = 0; o < 32; o += 4) {
                const float4 fv = *reinterpret_cast<const float4*>(&FS[s][o]);
                float e;
                e = fdr[o+0] + fv.x; e = fmaxf(e, 0.2f * e); c0 = fmaf(av[o+0], e, c0);
                e = fdr[o+1] + fv.y; e = fmaxf(e, 0.2f * e); c1 = fmaf(av[o+1], e, c1);
                e = fdr[o+2] + fv.z; e = fmaxf(e, 0.2f * e); c2 = fmaf(av[o+2], e, c2);
                e = fdr[o+3] + fv.w; e = fmaxf(e, 0.2f * e); c3 = fmaf(av[o+3], e, c3);
            }
            P[d][s] = (c0 + c1) + (c2 + c3);
        }
    }
    __syncthreads();

    if (tid < 128) {
        const int d = tid;
        float m = -1e30f;
        #pragma unroll 1
        for (int s = 0; s < 128; ++s) { float v = P[d][s]; m = (s == d) ? m : fmaxf(m, v); }
        float sum = 0.f;
        #pragma unroll 1
        for (int s = 0; s < 128; ++s) {
            float p = (s == d) ? 0.f : __expf(P[d][s] - m);
            P[d][s] = p; sum += p;
        }
        RN[d] = fast_rcp(sum);
    }
    __syncthreads();

    // PV -> FD (reused as output tile)
    {
        const int d = tid >> 1, oh = (tid & 1) * 16;
        float acc[16];
        #pragma unroll
        for (int i = 0; i < 16; ++i) acc[i] = 0.f;
        #pragma unroll 1
        for (int s = 0; s < 128; ++s) {
            const float p = P[d][s];
            #pragma unroll
            for (int oo = 0; oo < 16; oo += 4) {
                const float4 fv = *reinterpret_cast<const float4*>(&FS[s][oh + oo]);
                acc[oo+0] = fmaf(p, fv.x, acc[oo+0]);
                acc[oo+1] = fmaf(p, fv.y, acc[oo+1]);
                acc[oo+2] = fmaf(p, fv.z, acc[oo+2]);
                acc[oo+3] = fmaf(p, fv.w, acc[oo+3]);
            }
        }
        const float rz = RN[d];
        const float* bp = b2 + oh;
        #pragma unroll
        for (int oo = 0; oo < 16; ++oo) FD[d][oh + oo] = fmaf(acc[oo], rz, bp[oo]);
    }
    __syncthreads();

    // pooled[g][o] = mean over n
    {
        const int o = tid & 31, nb = tid >> 5;
        float sp = 0.f;
        #pragma unroll 1
        for (int n = nb * 16; n < nb * 16 + 16; ++n) sp += FD[n][o];
        PART[nb][o] = sp;
    }
    __syncthreads();
    if (tid < 32) {
        float s = 0.f;
        #pragma unroll
        for (int q = 0; q < 8; ++q) s += PART[q][tid];
        pooled[g * 32 + tid] = s * (1.f / 128.f);
    }
}

// ---------------------------------------------------------------------------
// Final: cosine sims, contrastive loss, output assembly.
// ---------------------------------------------------------------------------
__global__ void final_kernel(const float* __restrict__ pooled,
                             const float* __restrict__ hideout,
                             const float* __restrict__ timestep,
                             float* __restrict__ out)
{
    const int b = threadIdx.x;
    __shared__ float lossArr[16];
    if (b < 16) {
        const float* A  = pooled + b * 32;
        const float* Pv = pooled + (16 + b) * 32;
        float av[32];
        float na = 0.f;
        #pragma unroll
        for (int i = 0; i < 32; ++i) { av[i] = A[i]; na += av[i] * av[i]; }
        float npv = 0.f, dp = 0.f;
        #pragma unroll
        for (int i = 0; i < 32; ++i) { float p = Pv[i]; npv += p * p; dp += av[i] * p; }
        const float eps = 1e-6f;
        const float ia = 1.f / fmaxf(sqrtf(na), eps);
        const float sp = dp * ia / fmaxf(sqrtf(npv), eps);
        float sn[4];
        #pragma unroll
        for (int k = 0; k < 4; ++k) {
            const float* Nv = pooled + (32 + b * 4 + k) * 32;
            float nn = 0.f, dn = 0.f;
            #pragma unroll
            for (int i = 0; i < 32; ++i) { float q = Nv[i]; nn += q * q; dn += av[i] * q; }
            sn[k] = dn * ia / fmaxf(sqrtf(nn), eps);
        }
        float m = sp;
        #pragma unroll
        for (int k = 0; k < 4; ++k) m = fmaxf(m, sn[k]);
        float Z = expf(sp - m);
        #pragma unroll
        for (int k = 0; k < 4; ++k) Z += expf(sn[k] - m);
        lossArr[b] = logf(Z) + m - sp;   // lse - sim_pos
        float* r = out + b * 35;
        #pragma unroll
        for (int i = 0; i < 32; ++i) r[i] = av[i];
        r[32] = hideout[b * 2];
        r[33] = hideout[b * 2 + 1];
        r[34] = timestep[b];
    }
    __syncthreads();
    if (b == 0) {
        float s = 0.f;
        #pragma unroll
        for (int i = 0; i < 16; ++i) s += lossArr[i];
        out[560] = s * (1.f / 16.f);
    }
}

extern "C" void kernel_launch(void* const* d_in, const int* in_sizes, int n_in,
                              void* d_out, int out_size, void* d_ws, size_t ws_size,
                              hipStream_t stream) {
    const float* anchor   = (const float*)d_in[0];
    const float* pos      = (const float*)d_in[1];
    const float* neg      = (const float*)d_in[2];
    const float* hideout  = (const float*)d_in[3];
    const float* timestep = (const float*)d_in[4];
    const float* Wih      = (const float*)d_in[5];
    const float* Whh      = (const float*)d_in[6];
    const float* b_lstm   = (const float*)d_in[7];
    const float* W1s      = (const float*)d_in[8];
    const float* W1d      = (const float*)d_in[9];
    const float* a1       = (const float*)d_in[10];
    const float* b1       = (const float*)d_in[11];
    const float* W2s      = (const float*)d_in[12];
    const float* W2d      = (const float*)d_in[13];
    const float* a2       = (const float*)d_in[14];
    const float* b2       = (const float*)d_in[15];
    float* out = (float*)d_out;

    char* ws = (char*)d_ws;
    float* hn      = (float*)(ws);                       // 12288*32*4   = 1,572,864 B
    float* h1heads = (float*)(ws + 1605632);             // 96*8*128*32*4 = 12,582,912 B
    float* pooled  = (float*)(ws + 14188544);            // 96*32*4      = 12,288 B

    hipLaunchKernelGGL(lstm_mfma_kernel, dim3(768), dim3(128), 0, stream,
                       anchor, pos, neg, Wih, Whh, b_lstm, hn);
    hipLaunchKernelGGL(gat1_kernel,  dim3(768),  dim3(256), 0, stream,
                       hn, W1s, W1d, a1, b1, h1heads);
    hipLaunchKernelGGL(gat2_kernel,  dim3(96),   dim3(256), 0, stream,
                       h1heads, W2s, W2d, a2, b2, pooled);
    hipLaunchKernelGGL(final_kernel, dim3(1),    dim3(64),  0, stream,
                       pooled, hideout, timestep, out);
}